// Round 8
// baseline (44.389 us; speedup 1.0000x reference)
//
#include <hip/hip_runtime.h>
#include <hip/hip_bf16.h>

#define B_   2
#define L_   2048
#define C_   256
#define H_   8
#define DK_  32
#define HD_  256
#define RSQRT_DK 0.17677669529663687f  // 1/sqrt(32)

typedef __attribute__((ext_vector_type(8))) short bf16x8;
typedef __attribute__((ext_vector_type(4))) float f32x4;

__device__ __forceinline__ unsigned short f2bf(float x) {
    unsigned int u = __float_as_uint(x);
    u += 0x7fffu + ((u >> 16) & 1u);
    return (unsigned short)(u >> 16);
}
__device__ __forceinline__ float bf2f(unsigned short h) {
    return __uint_as_float((unsigned int)h << 16);
}

// LDS weight-slice layout (per 64x256 plane): idx = WT_IDX(n, k), shorts.
// Row pitch 256 shorts = 128 dwords (uniform bank base per row); 16B chunk
// swizzle chunk' = chunk ^ (n & 7) keeps b128 reads/writes at the bank floor.
#define WT_IDX(n, k) (((n) << 8) + (((((k) >> 3) ^ ((n) & 7))) << 3) + ((k) & 7))

// ---------------------------------------------------------------------------
// P0: one-time conversion.
//  Blocks 0..63    : transpose + split W{Q,K,V,O} (fp32 [k][n]) -> wT[p] =
//                    hi/lo bf16 [n][k] in global ws (round-3 kernel, proven).
//  Blocks 64..1599 : stream-convert qx/kx/vx -> Ah/Al bf16 [4096][256].
// ---------------------------------------------------------------------------
__global__ __launch_bounds__(256) void prep_kernel(
    const float* __restrict__ qx, const float* __restrict__ kx, const float* __restrict__ vx,
    const float* __restrict__ WQ, const float* __restrict__ WK,
    const float* __restrict__ WV, const float* __restrict__ WO,
    unsigned short* __restrict__ wT,
    unsigned short* __restrict__ ah, unsigned short* __restrict__ al)
{
    __shared__ float ts[64][65];
    const int blk = blockIdx.x;
    const int t = threadIdx.x;

    if (blk < 64) {
        const int p = blk >> 4, tile = blk & 15;
        const int k0 = (tile >> 2) * 64, n0 = (tile & 3) * 64;
        const float* W = p == 0 ? WQ : (p == 1 ? WK : (p == 2 ? WV : WO));
        unsigned short* Th = wT + (size_t)p * 131072;
        unsigned short* Tl = Th + 65536;

        const int r = t >> 2, cq = (t & 3) * 16;
        #pragma unroll
        for (int u = 0; u < 4; ++u) {
            float4 w4 = *reinterpret_cast<const float4*>(&W[(size_t)(k0 + r) * 256 + n0 + cq + u * 4]);
            ts[r][cq + u * 4 + 0] = w4.x;
            ts[r][cq + u * 4 + 1] = w4.y;
            ts[r][cq + u * 4 + 2] = w4.z;
            ts[r][cq + u * 4 + 3] = w4.w;
        }
        __syncthreads();
        bf16x8 hv0, hv1, lv0, lv1;
        #pragma unroll
        for (int e = 0; e < 8; ++e) {
            float x0 = ts[cq + e][r];
            float x1 = ts[cq + 8 + e][r];
            unsigned short h0 = f2bf(x0), h1 = f2bf(x1);
            hv0[e] = (short)h0;  lv0[e] = (short)f2bf(x0 - bf2f(h0));
            hv1[e] = (short)h1;  lv1[e] = (short)f2bf(x1 - bf2f(h1));
        }
        const size_t o = (size_t)(n0 + r) * 256 + k0 + cq;
        *reinterpret_cast<bf16x8*>(&Th[o])     = hv0;
        *reinterpret_cast<bf16x8*>(&Th[o + 8]) = hv1;
        *reinterpret_cast<bf16x8*>(&Tl[o])     = lv0;
        *reinterpret_cast<bf16x8*>(&Tl[o + 8]) = lv1;
    } else {
        const int blk2 = blk - 64;                 // 0..1535
        const int proj = blk2 >> 9;                // 512 blocks per proj
        const int ci = (blk2 & 511) * 256 + t;     // 8-float chunk id, 0..131071
        const float* src = proj == 0 ? qx : (proj == 1 ? kx : vx);
        const float* p = src + (size_t)ci * 8;
        float4 x0 = *reinterpret_cast<const float4*>(p);
        float4 x1 = *reinterpret_cast<const float4*>(p + 4);
        float xs[8] = {x0.x, x0.y, x0.z, x0.w, x1.x, x1.y, x1.z, x1.w};
        bf16x8 hv, lv;
        #pragma unroll
        for (int e = 0; e < 8; ++e) {
            const unsigned short h = f2bf(xs[e]);
            hv[e] = (short)h;
            lv[e] = (short)f2bf(xs[e] - bf2f(h));
        }
        const size_t o = (size_t)proj * 1048576 + (size_t)ci * 8;
        *reinterpret_cast<bf16x8*>(&ah[o]) = hv;
        *reinterpret_cast<bf16x8*>(&al[o]) = lv;
    }
}

// Copy a pre-converted 64-col weight slice (cols n0..n0+63, k 0..255) from
// global wT plane into swizzled LDS.  Pure bf16x8 copy, fully coalesced.
__device__ __forceinline__ void stage_wT_copy(
    const unsigned short* __restrict__ wTp, int n0, int tid,
    short* __restrict__ WTh, short* __restrict__ WTl)
{
    #pragma unroll
    for (int it = 0; it < 8; ++it) {
        const int c = tid + it * 256;      // chunk 0..2047
        const int n = c >> 5, k8 = c & 31;
        const size_t go = (size_t)(n0 + n) * 256 + k8 * 8;
        const int o = (n << 8) + ((k8 ^ (n & 7)) << 3);
        *reinterpret_cast<bf16x8*>(&WTh[o]) = *reinterpret_cast<const bf16x8*>(&wTp[go]);
        *reinterpret_cast<bf16x8*>(&WTl[o]) = *reinterpret_cast<const bf16x8*>(&wTp[65536 + go]);
    }
}

// ---------------------------------------------------------------------------
// K1: QKV projection GEMM, all inputs pre-converted split-bf16.
// Grid (32, 12 = proj*4 + nt), 256 thr = 4 waves; block tile 128x64,
// wave tile 32x64.  Inner loop: pure global-bf16x8 A frags + LDS B frags
// + MFMA.  Also emits deterministic per-block V column-sum partials.
// ---------------------------------------------------------------------------
__global__ __launch_bounds__(256) void gemm_qkv_fused(
    const unsigned short* __restrict__ ah, const unsigned short* __restrict__ al,
    const unsigned short* __restrict__ wT,
    const float* __restrict__ bQ, const float* __restrict__ bK, const float* __restrict__ bV,
    float* __restrict__ q, float* __restrict__ k, float* __restrict__ v,
    float* __restrict__ part)
{
    const int bx = blockIdx.x;          // 0..31
    const int yy = blockIdx.y;          // 0..11
    const int proj = yy >> 2, nt = yy & 3;
    const float* bias = proj == 0 ? bQ : (proj == 1 ? bK : bV);
    float* out        = proj == 0 ? q  : (proj == 1 ? k  : v);
    const unsigned short* Ah = ah + (size_t)proj * 1048576;
    const unsigned short* Al = al + (size_t)proj * 1048576;
    const int n0 = nt * 64;

    __shared__ short WTh[64 * 256];
    __shared__ short WTl[64 * 256];
    __shared__ float red[4][4][16];

    const int tid = threadIdx.x;
    stage_wT_copy(wT + (size_t)proj * 131072, n0, tid, WTh, WTl);
    __syncthreads();

    const int w  = tid >> 6;            // wave 0..3
    const int l  = tid & 63;
    const int lm = l & 15, lk8 = (l >> 4) * 8, cr = (l >> 4) * 4;
    const int R  = bx * 128 + w * 32;

    f32x4 acc[2][4];
    #pragma unroll
    for (int mf = 0; mf < 2; ++mf)
        #pragma unroll
        for (int nf = 0; nf < 4; ++nf)
            acc[mf][nf] = (f32x4){0.f, 0.f, 0.f, 0.f};

    bf16x8 Ahf[2][2], Alf[2][2];
    #define LOAD_A(buf, ks)                                                          \
    {                                                                                \
        const size_t o0 = (size_t)(R + lm) * C_ + (ks) * 32 + lk8;                   \
        const size_t o1 = (size_t)(R + 16 + lm) * C_ + (ks) * 32 + lk8;              \
        Ahf[buf][0] = *reinterpret_cast<const bf16x8*>(&Ah[o0]);                     \
        Ahf[buf][1] = *reinterpret_cast<const bf16x8*>(&Ah[o1]);                     \
        Alf[buf][0] = *reinterpret_cast<const bf16x8*>(&Al[o0]);                     \
        Alf[buf][1] = *reinterpret_cast<const bf16x8*>(&Al[o1]);                     \
    }
    LOAD_A(0, 0)
    LOAD_A(1, 1)

    #pragma unroll
    for (int ks = 0; ks < 8; ++ks) {
        const int cur = ks & 1;
        bf16x8 a_h[2] = {Ahf[cur][0], Ahf[cur][1]};
        bf16x8 a_l[2] = {Alf[cur][0], Alf[cur][1]};
        if (ks < 6) LOAD_A(cur, ks + 2)
        bf16x8 Bh[4], Bl[4];
        #pragma unroll
        for (int nf = 0; nf < 4; ++nf) {
            const int o = WT_IDX(nf * 16 + lm, ks * 32 + lk8);
            Bh[nf] = *reinterpret_cast<const bf16x8*>(&WTh[o]);
            Bl[nf] = *reinterpret_cast<const bf16x8*>(&WTl[o]);
        }
        #pragma unroll
        for (int mf = 0; mf < 2; ++mf)
            #pragma unroll
            for (int nf = 0; nf < 4; ++nf) {
                acc[mf][nf] = __builtin_amdgcn_mfma_f32_16x16x32_bf16(a_h[mf], Bh[nf], acc[mf][nf], 0, 0, 0);
                acc[mf][nf] = __builtin_amdgcn_mfma_f32_16x16x32_bf16(a_h[mf], Bl[nf], acc[mf][nf], 0, 0, 0);
                acc[mf][nf] = __builtin_amdgcn_mfma_f32_16x16x32_bf16(a_l[mf], Bh[nf], acc[mf][nf], 0, 0, 0);
            }
    }
    #undef LOAD_A

    // epilogue: bias + scatter to (B,H,L,DK)
    #pragma unroll
    for (int mf = 0; mf < 2; ++mf)
        #pragma unroll
        for (int nf = 0; nf < 4; ++nf) {
            const int col = n0 + nf * 16 + lm;
            const int h = col >> 5, d = col & 31;
            const float bb = bias[col];
            #pragma unroll
            for (int r = 0; r < 4; ++r) {
                const int m = R + mf * 16 + cr + r;
                const int b = m >> 11, lrow = m & (L_ - 1);
                out[((size_t)(b * H_ + h) * L_ + lrow) * DK_ + d] = acc[mf][nf][r] + bb;
            }
        }

    // V column-sum partials (deterministic, per block = 128 rows x 64 cols)
    if (proj == 2) {
        float sl[4];
        #pragma unroll
        for (int nf = 0; nf < 4; ++nf) {
            float s = 0.f;
            #pragma unroll
            for (int mf = 0; mf < 2; ++mf)
                #pragma unroll
                for (int r = 0; r < 4; ++r) s += acc[mf][nf][r];
            s += __shfl_xor(s, 16);
            s += __shfl_xor(s, 32);
            sl[nf] = s;
        }
        if (l < 16) {
            #pragma unroll
            for (int nf = 0; nf < 4; ++nf) red[w][nf][l] = sl[nf];
        }
        __syncthreads();
        if (tid < 64) {
            const int nf = tid >> 4, lmm = tid & 15;
            float tot = red[0][nf][lmm] + red[1][nf][lmm] + red[2][nf][lmm] + red[3][nf][lmm];
            const int col = n0 + nf * 16 + lmm;
            tot += 128.f * bias[col];
            const int h = col >> 5, d = col & 31;
            const int bh = (bx >> 4) * H_ + h;       // block spans one b
            part[((size_t)bh * 32 + d) * 16 + (bx & 15)] = tot;
        }
    }
}

// ---------------------------------------------------------------------------
// K2: attention.
//  Blocks 0..511   : interior rows, ONE ROW PER LANE, 64-row chunks
//                    (bh = blk>>5, chunk = blk&31).  K/V/Q staged in LDS,
//                    XOR-quad swizzle.
//  Blocks 512..1023: global-row partials (bh, row-pair, 128-col chunk).
// 128 threads (2 waves) per block.
// ---------------------------------------------------------------------------
#define NSLOT 200            // 68 K + 68 V + 64 Q
#define VOFF  68
#define QOFF  136

__global__ __launch_bounds__(128) void attn_main(
    const float* __restrict__ q, const float* __restrict__ k,
    const float* __restrict__ v, const float* __restrict__ part,
    float* __restrict__ pm, float* __restrict__ pZ, float* __restrict__ pzv,
    unsigned short* __restrict__ zh, unsigned short* __restrict__ zl)
{
    __shared__ float Sf[NSLOT * 32 + 32];
    float* vs_sh = &Sf[NSLOT * 32];

    // logical (slot, quad, elem) -> phys dword: slot*32 + ((quad ^ (slot&7))<<2) + elem
    #define LDS_F4(slot, u2) (*reinterpret_cast<const float4*>(&Sf[((slot) << 5) + (((u2) ^ ((slot) & 7)) << 2)]))

    const int blk = blockIdx.x;
    const int t = threadIdx.x;

    if (blk < 512) {
        // ----------------- interior rows, per-lane, 64-row chunks -----------------
        const int bh = blk >> 5, c = blk & 31;
        const int base = c * 64;                    // K/V slot s (<66) = row base+s
        const float* qb = q + (size_t)bh * L_ * DK_;
        const float* kb = k + (size_t)bh * L_ * DK_;
        const float* vb = v + (size_t)bh * L_ * DK_;

        // stage K(68 slots) V(68) Q(64) = 1600 float4 units
        for (int u = t; u < NSLOT * 8; u += 128) {
            const int slot = u >> 3, quad = u & 7;
            int row; const float* src;
            if (slot < VOFF) {
                const int s = slot;
                row = (s < 66) ? min(base + s, L_ - 1) : ((s == 66) ? 0 : L_ - 1);
                src = kb;
            } else if (slot < QOFF) {
                const int s = slot - VOFF;
                row = (s < 66) ? min(base + s, L_ - 1) : ((s == 66) ? 0 : L_ - 1);
                src = vb;
            } else {
                row = min(base + 1 + (slot - QOFF), L_ - 1);
                src = qb;
            }
            float4 w4 = *reinterpret_cast<const float4*>(&src[(size_t)row * DK_ + quad * 4]);
            float* dst = &Sf[(slot << 5) + ((quad ^ (slot & 7)) << 2)];
            dst[0] = w4.x; dst[1] = w4.y; dst[2] = w4.z; dst[3] = w4.w;
        }
        if (t < 32) {
            const float4* pp = reinterpret_cast<const float4*>(&part[((size_t)bh * 32 + t) * 16]);
            float4 pa = pp[0], pb = pp[1], pc = pp[2], pd = pp[3];
            vs_sh[t] = pa.x + pa.y + pa.z + pa.w + pb.x + pb.y + pb.z + pb.w
                     + pc.x + pc.y + pc.z + pc.w + pd.x + pd.y + pd.z + pd.w;
        }
        __syncthreads();

        const int i = base + 1 + t;
        if (t < 64 && i <= L_ - 2) {
            float qr[32];
            {
                const int qs = QOFF + t;
                #pragma unroll
                for (int u2 = 0; u2 < 8; ++u2) {
                    float4 x = LDS_F4(qs, u2);
                    qr[u2 * 4 + 0] = x.x; qr[u2 * 4 + 1] = x.y;
                    qr[u2 * 4 + 2] = x.z; qr[u2 * 4 + 3] = x.w;
                }
            }
            const int ks_[5] = {66, t, t + 1, t + 2, 67};   // cols 0, i-1, i, i+1, L-1
            float sv[5];
            #pragma unroll
            for (int jj = 0; jj < 5; ++jj) {
                const int s = ks_[jj];
                float p = 0.f;
                #pragma unroll
                for (int u2 = 0; u2 < 8; ++u2) {
                    float4 kv = LDS_F4(s, u2);
                    p += qr[u2 * 4 + 0] * kv.x + qr[u2 * 4 + 1] * kv.y
                       + qr[u2 * 4 + 2] * kv.z + qr[u2 * 4 + 3] * kv.w;
                }
                sv[jj] = p * RSQRT_DK;
            }
            const bool v1 = (i != 1), v3 = (i != L_ - 2);
            float m = fmaxf(0.f, sv[0]);                 // zero fillers join the max
            m = fmaxf(m, sv[2]); m = fmaxf(m, sv[4]);
            if (v1) m = fmaxf(m, sv[1]);
            if (v3) m = fmaxf(m, sv[3]);
            float e[5];
            e[0] = __expf(sv[0] - m);
            e[1] = v1 ? __expf(sv[1] - m) : 0.f;
            e[2] = __expf(sv[2] - m);
            e[3] = v3 ? __expf(sv[3] - m) : 0.f;
            e[4] = __expf(sv[4] - m);
            const int ns = 3 + (int)v1 + (int)v3;
            const float e0 = __expf(-m);
            const float Z = e[0] + e[1] + e[2] + e[3] + e[4] + (float)(L_ - ns) * e0;
            const float rZ = 1.f / Z;
            const float f1 = v1 ? 1.f : 0.f, f3 = v3 ? 1.f : 0.f;

            bf16x8 zh8[4], zl8[4];
            #pragma unroll
            for (int u2 = 0; u2 < 8; ++u2) {
                float4 x0 = LDS_F4(VOFF + 66,    u2);
                float4 x1 = LDS_F4(VOFF + t,     u2);
                float4 x2 = LDS_F4(VOFF + t + 1, u2);
                float4 x3 = LDS_F4(VOFF + t + 2, u2);
                float4 x4 = LDS_F4(VOFF + 67,    u2);
                float a0[4] = {x0.x, x0.y, x0.z, x0.w};
                float a1[4] = {x1.x, x1.y, x1.z, x1.w};
                float a2[4] = {x2.x, x2.y, x2.z, x2.w};
                float a3[4] = {x3.x, x3.y, x3.z, x3.w};
                float a4[4] = {x4.x, x4.y, x4.z, x4.w};
                #pragma unroll
                for (int e2 = 0; e2 < 4; ++e2) {
                    const int d = u2 * 4 + e2;
                    const float num = e[0] * a0[e2] + e[1] * a1[e2] + e[2] * a2[e2]
                                    + e[3] * a3[e2] + e[4] * a4[e2];
                    const float vp = a0[e2] + f1 * a1[e2] + a2[e2] + f3 * a3[e2] + a4[e2];
                    const float zd = (num + e0 * (vs_sh[d] - vp)) * rZ;
                    const unsigned short hb = f2bf(zd);
                    zh8[d >> 3][d & 7] = (short)hb;
                    zl8[d >> 3][d & 7] = (short)f2bf(zd - bf2f(hb));
                }
            }
            const int b = bh >> 3, h = bh & 7;
            const size_t o = (size_t)(b * L_ + i) * HD_ + h * DK_;
            #pragma unroll
            for (int u4 = 0; u4 < 4; ++u4) {
                *reinterpret_cast<bf16x8*>(&zh[o + u4 * 8]) = zh8[u4];
                *reinterpret_cast<bf16x8*>(&zl[o + u4 * 8]) = zl8[u4];
            }
        }
    } else {
        // ----------------- global-row partials -----------------
        const int blk2 = blk - 512;                 // 0..511
        const int bh = blk2 >> 5;
        const int pair = (blk2 >> 4) & 1;
        const int chunk = blk2 & 15;
        const int r = pair ? (L_ - 1) : 0;
        const int j0 = chunk * 128;
        const float* qb = q + (size_t)bh * L_ * DK_;
        const float* kb = k + (size_t)bh * L_ * DK_;
        const float* vb = v + (size_t)bh * L_ * DK_;

        float* qs  = Sf;          // 32
        float* sc  = Sf + 32;     // 128
        float* red = Sf + 160;    // 4
        float* pzs = Sf + 192;    // 128

        if (t < 32) qs[t] = qb[(size_t)r * DK_ + t];
        __syncthreads();

        const int j = j0 + t;
        const float4* kr = reinterpret_cast<const float4*>(&kb[(size_t)j * DK_]);
        float p = 0.f;
        #pragma unroll
        for (int u = 0; u < 8; ++u) {
            float4 kv = kr[u];
            p += qs[u * 4 + 0] * kv.x + qs[u * 4 + 1] * kv.y
               + qs[u * 4 + 2] * kv.z + qs[u * 4 + 3] * kv.w;
        }
        p *= RSQRT_DK;

        float lm = p;
        #pragma unroll
        for (int off = 32; off; off >>= 1) lm = fmaxf(lm, __shfl_xor(lm, off, 64));
        if ((t & 63) == 0) red[t >> 6] = lm;
        __syncthreads();
        const float m = fmaxf(red[0], red[1]);

        const float e = __expf(p - m);
        sc[t] = e;
        float ls = e;
        #pragma unroll
        for (int off = 32; off; off >>= 1) ls += __shfl_xor(ls, off, 64);
        if ((t & 63) == 0) red[2 + (t >> 6)] = ls;
        __syncthreads();
        const float Zc = red[2] + red[3];

        const int d = t & 31, g = t >> 5;
        float acc = 0.f;
        #pragma unroll 4
        for (int jj = 0; jj < 32; ++jj)
            acc += sc[g * 32 + jj] * vb[(size_t)(j0 + g * 32 + jj) * DK_ + d];
        pzs[g * 32 + d] = acc;
        __syncthreads();
        if (g == 0) {
            const float s2 = pzs[d] + pzs[32 + d] + pzs[64 + d] + pzs[96 + d];
            pzv[(size_t)blk2 * 32 + d] = s2;
        }
        if (t == 0) { pm[blk2] = m; pZ[blk2] = Zc; }
    }
    #undef LDS_F4
}

// ---------------------------------------------------------------------------
// K2b: combine 16 chunks per global row; write z hi/lo.  1 block.
// ---------------------------------------------------------------------------
__global__ __launch_bounds__(1024) void attn_g2_kernel(
    const float* __restrict__ pm, const float* __restrict__ pZ,
    const float* __restrict__ pzv,
    unsigned short* __restrict__ zh, unsigned short* __restrict__ zl)
{
    const int t = threadIdx.x;           // 0..1023
    const int rowIdx = t >> 5;           // 0..31 (= bh*2 + pair)
    const int d = t & 31;
    const int bh = rowIdx >> 1, pair = rowIdx & 1;
    const int base = rowIdx * 16;

    float m = -1e30f;
    #pragma unroll
    for (int c = 0; c < 16; ++c) m = fmaxf(m, pm[base + c]);
    float Z = 0.f, zd = 0.f;
    #pragma unroll
    for (int c = 0; c < 16; ++c) {
        const float w = __expf(pm[base + c] - m);
        Z  += pZ[base + c] * w;
        zd += pzv[(size_t)(base + c) * 32 + d] * w;
    }
    zd /= Z;

    const int r = pair ? (L_ - 1) : 0;
    const int b = bh >> 3, h = bh & 7;
    const size_t o = (size_t)(b * L_ + r) * HD_ + h * DK_ + d;
    const unsigned short hb = f2bf(zd);
    zh[o] = hb;
    zl[o] = f2bf(zd - bf2f(hb));
}

// ---------------------------------------------------------------------------
// K3: out = z @ WO + bO via split-bf16 MFMA; WO slice copied pre-converted
// from global wT[3].  Grid (64, 4), 256 thr = 4 waves; block tile 64x64,
// wave tile 16x64.
// ---------------------------------------------------------------------------
__global__ __launch_bounds__(256) void gemm_out_fused(
    const unsigned short* __restrict__ zh, const unsigned short* __restrict__ zl,
    const unsigned short* __restrict__ wT, const float* __restrict__ bO,
    float* __restrict__ out)
{
    const int bx = blockIdx.x;          // 0..63
    const int nt = blockIdx.y;          // 0..3
    const int n0 = nt * 64;

    __shared__ short WTh[64 * 256];
    __shared__ short WTl[64 * 256];

    const int tid = threadIdx.x;
    stage_wT_copy(wT + (size_t)3 * 131072, n0, tid, WTh, WTl);
    __syncthreads();

    const int w  = tid >> 6;
    const int l  = tid & 63;
    const int lm = l & 15, lk8 = (l >> 4) * 8, cr = (l >> 4) * 4;
    const int R  = bx * 64 + w * 16;

    f32x4 acc[4];
    #pragma unroll
    for (int nf = 0; nf < 4; ++nf) acc[nf] = (f32x4){0.f, 0.f, 0.f, 0.f};

    bf16x8 Ah[2], Al[2];
    #define LOAD_Z(buf, ks)                                                          \
    {                                                                                \
        const size_t o = (size_t)(R + lm) * HD_ + (ks) * 32 + lk8;                   \
        Ah[buf] = *reinterpret_cast<const bf16x8*>(&zh[o]);                          \
        Al[buf] = *reinterpret_cast<const bf16x8*>(&zl[o]);                          \
    }
    LOAD_Z(0, 0)
    LOAD_Z(1, 1)

    #pragma unroll
    for (int ks = 0; ks < 8; ++ks) {
        const int cur = ks & 1;
        const bf16x8 a_h = Ah[cur], a_l = Al[cur];
        if (ks < 6) LOAD_Z(cur, ks + 2)
        #pragma unroll
        for (int nf = 0; nf < 4; ++nf) {
            const int o = WT_IDX(nf * 16 + lm, ks * 32 + lk8);
            const bf16x8 b_h = *reinterpret_cast<const bf16x8*>(&WTh[o]);
            const bf16x8 b_l = *reinterpret_cast<const bf16x8*>(&WTl[o]);
            acc[nf] = __builtin_amdgcn_mfma_f32_16x16x32_bf16(a_h, b_h, acc[nf], 0, 0, 0);
            acc[nf] = __builtin_amdgcn_mfma_f32_16x16x32_bf16(a_h, b_l, acc[nf], 0, 0, 0);
            acc[nf] = __builtin_amdgcn_mfma_f32_16x16x32_bf16(a_l, b_h, acc[nf], 0, 0, 0);
        }
    }
    #undef LOAD_Z

    #pragma unroll
    for (int nf = 0; nf < 4; ++nf) {
        const int col = n0 + nf * 16 + lm;
        const float bb = bO[col];
        #pragma unroll
        for (int r = 0; r < 4; ++r) {
            const int m = R + cr + r;
            out[(size_t)m * HD_ + col] = acc[nf][r] + bb;
        }
    }
}

// ---------------------------------------------------------------------------
extern "C" void kernel_launch(void* const* d_in, const int* in_sizes, int n_in,
                              void* d_out, int out_size, void* d_ws, size_t ws_size,
                              hipStream_t stream)
{
    const float* qx = (const float*)d_in[0];
    const float* kx = (const float*)d_in[1];
    const float* vx = (const float*)d_in[2];
    const float* WQ = (const float*)d_in[3];
    const float* bQ = (const float*)d_in[4];
    const float* WK = (const float*)d_in[5];
    const float* bK = (const float*)d_in[6];
    const float* WV = (const float*)d_in[7];
    const float* bV = (const float*)d_in[8];
    const float* WO = (const float*)d_in[9];
    const float* bO = (const float*)d_in[10];
    float* out = (float*)d_out;

    char* wsb = (char*)d_ws;
    float*          q    = (float*)(wsb);                            // 4 MB
    float*          k    = (float*)(wsb + (4u  << 20));              // 4 MB
    float*          v    = (float*)(wsb + (8u  << 20));              // 4 MB
    unsigned short* zh   = (unsigned short*)(wsb + (12u << 20));     // 2 MB
    unsigned short* zl   = (unsigned short*)(wsb + (14u << 20));     // 2 MB
    unsigned short* wT   = (unsigned short*)(wsb + (16u << 20));     // 1 MB
    float*          part = (float*)(wsb + (17u << 20));              // 32 KB
    float*          pm   = (float*)(wsb + (17u << 20) + (1u << 16)); // 512 f
    float*          pZ   = pm + 512;
    float*          pzv  = pm + 1024;                                // 16384 f
    unsigned short* ah   = (unsigned short*)(wsb + (18u << 20));     // 6 MB
    unsigned short* al   = (unsigned short*)(wsb + (24u << 20));     // 6 MB

    prep_kernel<<<1600, 256, 0, stream>>>(qx, kx, vx, WQ, WK, WV, WO, wT, ah, al);
    gemm_qkv_fused<<<dim3(32, 12), 256, 0, stream>>>(ah, al, wT, bQ, bK, bV, q, k, v, part);
    attn_main<<<1024, 128, 0, stream>>>(q, k, v, part, pm, pZ, pzv, zh, zl);
    attn_g2_kernel<<<1, 1024, 0, stream>>>(pm, pZ, pzv, zh, zl);
    gemm_out_fused<<<dim3(64, 4), 256, 0, stream>>>(zh, zl, wT, bO, out);
}